// Round 4
// baseline (10816.288 us; speedup 1.0000x reference)
//
#include <hip/hip_runtime.h>
#include <math.h>

// SupervisedClusteringLoss: two Prim MSTs (gold / violation graphs) on a
// 4096x4096 symmetric score matrix, then a scalar combine.
//
// KEY SEMANTIC (verified by tracing the JAX reference): once the frontier of
// the component containing node 0 is exhausted, argmin over an all-inf array
// returns index 0 (already in tree) forever -> the reference only spans the
// connected component of node 0. We replicate that with an early break when
// the frontier min is +inf.
//
// Exactness vs reference: argmin tie-break = lowest index (jnp.argmin first
// occurrence); relax uses strict < (keeps old parent on ties). With both
// matched, we select the exact same edge sequence as the JAX loop.

constexpr int N_NODES = 4096;
constexpr int NTHR    = 1024;
constexpr int PT      = 4;      // nodes per thread, consecutive -> float4 row loads
constexpr int NWAVE   = NTHR / 64;

__global__ __launch_bounds__(NTHR, 1)
void prim_mst_kernel(const float* __restrict__ S,
                     const int* __restrict__ intents,
                     double* __restrict__ ws)
{
    const int graph = blockIdx.x;   // 0 = gold graph, 1 = violation graph
    const int tid   = threadIdx.x;
    const int lane  = tid & 63;
    const int wid   = tid >> 6;
    const int base  = tid * PT;

    __shared__ int    s_int[N_NODES];
    __shared__ float  s_redv[2][NWAVE];   // parity double-buffer (1 barrier/iter)
    __shared__ int    s_redi[2][NWAVE];
    __shared__ double s_accA;   // gold: edge count a   | viol: b (eq edges)
    __shared__ double s_accB;   // gold: unused         | viol: c (neq edges)
    __shared__ double s_accC;   // sum of selected edge weights (dj)

    for (int i = tid; i < N_NODES; i += NTHR) s_int[i] = intents[i];
    if (tid == 0) { s_accA = 0.0; s_accB = 0.0; s_accC = 0.0; }
    __syncthreads();

    int   myint[PT];
    float dist[PT];
    int   par[PT];
    bool  intree[PT];

    #pragma unroll
    for (int k = 0; k < PT; ++k) {
        myint[k]  = s_int[base + k];
        par[k]    = 0;                    // parent0 = zeros
        intree[k] = (base + k) == 0;      // node 0 starts in tree
    }

    const float INF  = __builtin_inff();
    const int   int0 = s_int[0];

    // dist0 = where(i==0, inf, E[0][i])
    {
        const float4 s4 = *reinterpret_cast<const float4*>(S + base);
        const float sv[PT] = {s4.x, s4.y, s4.z, s4.w};
        #pragma unroll
        for (int k = 0; k < PT; ++k) {
            const float s  = sv[k];
            const bool  eq = (myint[k] == int0);
            float w;
            if (graph == 0) {
                // gold_w = -S*eq ; absent (inf) when 0
                w = (eq && s != 0.0f) ? -s : INF;
            } else {
                // viol = S + 0.5*neq - 1.0*eq ; edge weight -viol when viol>0
                const float v = (s + (eq ? 0.0f : 0.5f)) - (eq ? 1.0f : 0.0f);
                w = (v > 0.0f) ? -v : INF;
            }
            dist[k] = ((base + k) == 0) ? INF : w;
        }
    }

    for (int it = 0; it < N_NODES - 1; ++it) {
        const int p = it & 1;
        // ---- local argmin over this thread's 4 nodes (ascending -> first-min)
        float lv = INF; int li = base;
        #pragma unroll
        for (int k = 0; k < PT; ++k) {
            if (!intree[k] && dist[k] < lv) { lv = dist[k]; li = base + k; }
        }
        // ---- wave64 butterfly argmin, tie-break lower index (matches jnp.argmin)
        #pragma unroll
        for (int m = 1; m < 64; m <<= 1) {
            const float ov = __shfl_xor(lv, m, 64);
            const int   oi = __shfl_xor(li, m, 64);
            if (ov < lv || (ov == lv && oi < li)) { lv = ov; li = oi; }
        }
        if (lane == 0) { s_redv[p][wid] = lv; s_redi[p][wid] = li; }
        __syncthreads();
        // ---- every thread reduces the 16 wave results (identical outcome)
        float dj = s_redv[p][0]; int j = s_redi[p][0];
        #pragma unroll
        for (int w = 1; w < NWAVE; ++w) {
            const float v = s_redv[p][w]; const int i2 = s_redi[p][w];
            if (v < dj || (v == dj && i2 < j)) { dj = v; j = i2; }
        }

        // Frontier empty: reference is a permanent no-op fixpoint from here on.
        if (dj == INF) break;

        // ---- owner thread: mark in-tree, accumulate edge stats (single writer)
        if ((j >> 2) == tid) {
            const int k = j & (PT - 1);
            intree[k] = true;
            if (graph == 0) {
                s_accA += 1.0;
            } else {
                if (myint[k] == s_int[par[k]]) s_accA += 1.0; else s_accB += 1.0;
            }
            s_accC += (double)dj;
        }

        // ---- relax with row j (coalesced float4 per thread)
        const int ij = s_int[j];
        const float4 s4 = *reinterpret_cast<const float4*>(S + (size_t)j * N_NODES + base);
        const float sv[PT] = {s4.x, s4.y, s4.z, s4.w};
        #pragma unroll
        for (int k = 0; k < PT; ++k) {
            if (intree[k]) continue;
            const float s  = sv[k];
            const bool  eq = (myint[k] == ij);
            float w;
            if (graph == 0) {
                w = (eq && s != 0.0f) ? -s : INF;
            } else {
                const float v = (s + (eq ? 0.0f : 0.5f)) - (eq ? 1.0f : 0.0f);
                w = (v > 0.0f) ? -v : INF;
            }
            if (w < dist[k]) { dist[k] = w; par[k] = j; }  // strict <, keep old parent on tie
        }
    }

    __syncthreads();
    if (tid == 0) {
        ws[graph * 3 + 0] = s_accA;
        ws[graph * 3 + 1] = s_accB;
        ws[graph * 3 + 2] = s_accC;
    }
}

__global__ void finalize_kernel(const double* __restrict__ ws,
                                float* __restrict__ out)
{
    const double a           = ws[0];   // gold edge count
    const double sum_dj_gold = ws[2];
    const double b           = ws[3];   // viol eq edges
    const double c           = ws[4];   // viol neq edges
    const double sum_dj_viol = ws[5];

    // gold edge weight d = -S  =>  gold_score = -sum(d)
    const double gold_score = -sum_dj_gold;
    // viol edge weight d = -(S + 0.5*neq - eq) => S = -d + eq - 0.5*neq
    const double viol_score = -sum_dj_viol + b - 0.5 * c;

    const double delta = a - b + 0.5 * c;          // C=1, R=0.5
    const double obj   = delta + viol_score - gold_score;
    const double loss  = (delta > 0.0) ? fmax(0.0, obj) : 0.0;
    out[0] = (float)loss;
}

extern "C" void kernel_launch(void* const* d_in, const int* in_sizes, int n_in,
                              void* d_out, int out_size, void* d_ws, size_t ws_size,
                              hipStream_t stream)
{
    const float* S       = (const float*)d_in[0];
    const int*   intents = (const int*)d_in[1];
    float*       out     = (float*)d_out;
    double*      ws      = (double*)d_ws;

    hipLaunchKernelGGL(prim_mst_kernel, dim3(2), dim3(NTHR), 0, stream, S, intents, ws);
    hipLaunchKernelGGL(finalize_kernel, dim3(1), dim3(1), 0, stream, ws, out);
}

// Round 5
// 10224.586 us; speedup vs baseline: 1.0579x; 1.0579x over previous
//
#include <hip/hip_runtime.h>
#include <math.h>

// SupervisedClusteringLoss: two Prim MSTs (gold / violation graphs) on a
// 4096x4096 symmetric score matrix, then a scalar combine.
//
// KEY SEMANTIC (verified by tracing the JAX reference): once the frontier of
// the component containing node 0 is exhausted, argmin over an all-inf array
// returns index 0 (already in tree) forever -> the reference only spans the
// connected component of node 0. We replicate that with an early break.
//
// This revision (round 4): baseline showed 2.78us/iter with VGPR_Count=24 ->
// the per-thread arrays were in SCRATCH (runtime-indexed owner update), plus
// 16 waves saturated the DS pipe (~620 DS ops/iter). Now: 256 thr x 16 nodes,
// dist held as packed u64 keys (mapped_weight<<32 | node<<1 | eq) in VGPRs
// with static indexing only; argmin = u64 tree-min (value, then lowest index
// = jnp.argmin first-occurrence); stats in register doubles.

constexpr int N_NODES = 4096;
constexpr int NTHR    = 256;
constexpr int PT      = 16;          // nodes per thread
constexpr int NWAVE   = NTHR / 64;   // 4

// monotone map: f32 -> u32 preserving order (smaller float -> smaller uint)
__device__ __forceinline__ unsigned mapf(float f) {
    unsigned u = __float_as_uint(f);
    return (u & 0x80000000u) ? ~u : (u | 0x80000000u);
}
__device__ __forceinline__ float unmapf(unsigned m) {
    unsigned u = (m & 0x80000000u) ? (m ^ 0x80000000u) : ~m;
    return __uint_as_float(u);
}
__device__ __forceinline__ unsigned long long kmin(unsigned long long a,
                                                   unsigned long long b) {
    return a < b ? a : b;
}

__global__ __launch_bounds__(NTHR, 1)
void prim_mst_kernel(const float* __restrict__ S,
                     const int* __restrict__ intents,
                     double* __restrict__ ws)
{
    const int graph = blockIdx.x;   // 0 = gold graph, 1 = violation graph
    const int tid   = threadIdx.x;
    const int lane  = tid & 63;
    const int wid   = tid >> 6;
    const int base  = tid * PT;

    __shared__ int                s_int[N_NODES];
    __shared__ unsigned long long s_red[2][NWAVE];   // parity dbuf, 1 barrier/iter
    __shared__ double             s_acc[NWAVE][3];

    for (int i = tid; i < N_NODES; i += NTHR) s_int[i] = intents[i];
    __syncthreads();

    int myint[PT];
    #pragma unroll
    for (int k = 0; k < PT; ++k) myint[k] = s_int[base + k];

    const float INF = __builtin_inff();
    const unsigned long long SENT = ~0ull;   // in-tree sentinel (> any inf key)
    const int int0 = s_int[0];

    unsigned long long key[PT];  // (mapf(weight)<<32) | (node<<1 | eqflag)
    unsigned intree = 0;

    // ---- init dist from row 0 (parent = 0)
    #pragma unroll
    for (int q = 0; q < PT / 4; ++q) {
        const float4 s4 = *reinterpret_cast<const float4*>(S + base + 4 * q);
        const float sv[4] = {s4.x, s4.y, s4.z, s4.w};
        #pragma unroll
        for (int r = 0; r < 4; ++r) {
            const int k    = 4 * q + r;
            const int node = base + k;
            const float s  = sv[r];
            const bool eq  = (myint[k] == int0);
            float w;
            if (graph == 0) {
                w = (eq && s != 0.0f) ? -s : INF;              // gold_w = -S*eq, 0 = absent
            } else {
                const float v = (s + (eq ? 0.0f : 0.5f)) - (eq ? 1.0f : 0.0f);
                w = (v > 0.0f) ? -v : INF;                     // viol hinge, negated
            }
            key[k] = ((unsigned long long)mapf(w) << 32)
                   | (unsigned)((node << 1) | (eq ? 1 : 0));
        }
    }
    if (tid == 0) { key[0] = SENT; intree |= 1u; }   // node 0 starts in tree

    double accA = 0.0, accB = 0.0, accC = 0.0;
    // gold: accA = a (edge count) | viol: accA = b (eq), accB = c (neq)
    // accC = sum of selected edge weights

    for (int it = 0; it < N_NODES - 1; ++it) {
        const int p = it & 1;

        // ---- depth-4 tree argmin over 16 packed keys (ties impossible: unique ids)
        unsigned long long b0 = kmin(key[0],  key[1]);
        unsigned long long b1 = kmin(key[2],  key[3]);
        unsigned long long b2 = kmin(key[4],  key[5]);
        unsigned long long b3 = kmin(key[6],  key[7]);
        unsigned long long b4 = kmin(key[8],  key[9]);
        unsigned long long b5 = kmin(key[10], key[11]);
        unsigned long long b6 = kmin(key[12], key[13]);
        unsigned long long b7 = kmin(key[14], key[15]);
        b0 = kmin(b0, b1); b2 = kmin(b2, b3); b4 = kmin(b4, b5); b6 = kmin(b6, b7);
        b0 = kmin(b0, b2); b4 = kmin(b4, b6);
        unsigned long long best = kmin(b0, b4);

        // ---- wave64 butterfly min (packed => value then lowest index)
        #pragma unroll
        for (int d = 1; d < 64; d <<= 1) {
            const unsigned long long o = __shfl_xor(best, d, 64);
            best = kmin(best, o);
        }
        if (lane == 0) s_red[p][wid] = best;
        __syncthreads();
        // ---- every thread min-reduces the 4 wave results (identical outcome)
        #pragma unroll
        for (int w = 0; w < NWAVE; ++w) best = kmin(best, s_red[p][w]);

        // Frontier empty (min is +inf or all in-tree): reference fixpoint -> stop.
        if ((unsigned)(best >> 32) >= 0xFF800000u) break;

        const int   jpacked = (int)(best & 0xFFFFFFFFu);
        const int   j       = jpacked >> 1;
        const int   ij      = s_int[j];
        const float dj      = unmapf((unsigned)(best >> 32));

        // issue row-j loads early (L3-resident; latency hides under stats)
        const float* row = S + (size_t)j * N_NODES + base;
        float4 r[PT / 4];
        #pragma unroll
        for (int q = 0; q < PT / 4; ++q)
            r[q] = *reinterpret_cast<const float4*>(row + 4 * q);

        // ---- owner bookkeeping (exactly one (thread,k) matches; static index)
        #pragma unroll
        for (int k = 0; k < PT; ++k) {
            if (base + k == j) {
                intree |= (1u << k);
                key[k] = SENT;
                if (graph == 0) accA += 1.0;
                else { if (jpacked & 1) accA += 1.0; else accB += 1.0; }
                accC += (double)dj;
            }
        }

        // ---- relax with row j
        #pragma unroll
        for (int q = 0; q < PT / 4; ++q) {
            const float sv[4] = {r[q].x, r[q].y, r[q].z, r[q].w};
            #pragma unroll
            for (int rr = 0; rr < 4; ++rr) {
                const int k = 4 * q + rr;
                if ((intree >> k) & 1u) continue;
                const float s  = sv[rr];
                const bool eq  = (myint[k] == ij);
                float w;
                if (graph == 0) {
                    w = (eq && s != 0.0f) ? -s : INF;
                } else {
                    const float v = (s + (eq ? 0.0f : 0.5f)) - (eq ? 1.0f : 0.0f);
                    w = (v > 0.0f) ? -v : INF;
                }
                const unsigned long long wk =
                    ((unsigned long long)mapf(w) << 32)
                    | (unsigned)(((base + k) << 1) | (eq ? 1 : 0));
                if (wk < key[k]) key[k] = wk;   // strict < : old entry kept on tie
            }
        }
    }

    // ---- block-sum the three accumulators (once)
    #pragma unroll
    for (int d = 1; d < 64; d <<= 1) {
        accA += __shfl_xor(accA, d, 64);
        accB += __shfl_xor(accB, d, 64);
        accC += __shfl_xor(accC, d, 64);
    }
    if (lane == 0) { s_acc[wid][0] = accA; s_acc[wid][1] = accB; s_acc[wid][2] = accC; }
    __syncthreads();
    if (tid == 0) {
        double A = 0.0, B = 0.0, Cs = 0.0;
        for (int w = 0; w < NWAVE; ++w) { A += s_acc[w][0]; B += s_acc[w][1]; Cs += s_acc[w][2]; }
        ws[graph * 3 + 0] = A;
        ws[graph * 3 + 1] = B;
        ws[graph * 3 + 2] = Cs;
    }
}

__global__ void finalize_kernel(const double* __restrict__ ws,
                                float* __restrict__ out)
{
    const double a           = ws[0];   // gold edge count
    const double sum_dj_gold = ws[2];
    const double b           = ws[3];   // viol eq edges
    const double c           = ws[4];   // viol neq edges
    const double sum_dj_viol = ws[5];

    // gold edge weight d = -S  =>  gold_score = -sum(d)
    const double gold_score = -sum_dj_gold;
    // viol edge weight d = -(S + 0.5*neq - eq) => S = -d + eq - 0.5*neq
    const double viol_score = -sum_dj_viol + b - 0.5 * c;

    const double delta = a - b + 0.5 * c;          // C=1, R=0.5
    const double obj   = delta + viol_score - gold_score;
    const double loss  = (delta > 0.0) ? fmax(0.0, obj) : 0.0;
    out[0] = (float)loss;
}

extern "C" void kernel_launch(void* const* d_in, const int* in_sizes, int n_in,
                              void* d_out, int out_size, void* d_ws, size_t ws_size,
                              hipStream_t stream)
{
    const float* S       = (const float*)d_in[0];
    const int*   intents = (const int*)d_in[1];
    float*       out     = (float*)d_out;
    double*      ws      = (double*)d_ws;

    hipLaunchKernelGGL(prim_mst_kernel, dim3(2), dim3(NTHR), 0, stream, S, intents, ws);
    hipLaunchKernelGGL(finalize_kernel, dim3(1), dim3(1), 0, stream, ws, out);
}

// Round 7
// 331.525 us; speedup vs baseline: 32.6258x; 30.8410x over previous
//
#include <hip/hip_runtime.h>
#include <math.h>

// SupervisedClusteringLoss via Borůvka MST (replaces sequential Prim).
//
// Loss invariance (verified by derivation): all MSTs of a graph share the
// same edge-weight multiset; per-edge contribution to obj depends only on
// weight (gold: 1+w ; viol eq: -w ; viol neq: -w). Expanding obj shows the
// b/c (eq/neq) counts cancel: obj = a - sum_w(viol) - gold_score; delta only
// feeds the >0 gate (margin ~2000). So ANY MST algorithm with a strict total
// edge order (w, lo, hi) reproduces the reference loss exactly.
// Reference semantics (traced fixpoint): only node-0's connected component
// is spanned -> we compute the full Borůvka forest, record chosen edges, and
// count only edges whose final component == node 0's component. Exact.

constexpr int N        = 4096;
constexpr int EDGE_CAP = 4608;                    // >= N-1 with slack
constexpr int ROUNDS   = 12;                      // comps at least halve/round
constexpr unsigned long long SENT = ~0ull;

// monotone f32 -> u32 order-preserving map
__device__ __forceinline__ unsigned mapf(float f) {
    unsigned u = __float_as_uint(f);
    return (u & 0x80000000u) ? ~u : (u | 0x80000000u);
}
__device__ __forceinline__ float unmapf(unsigned m) {
    unsigned u = (m & 0x80000000u) ? (m ^ 0x80000000u) : ~m;
    return __uint_as_float(u);
}

// edge weight + existence, bit-exact vs reference formulas
__device__ __forceinline__ bool edge_w(int graph, float s, bool eq, float& w) {
    if (graph == 0) { w = -s; return eq && (s != 0.0f); }          // gold_w=-S*eq, 0=absent
    const float v = (s + (eq ? 0.0f : 0.5f)) - (eq ? 1.0f : 0.0f); // viol hinge
    w = -v;
    return v > 0.0f;
}

__global__ __launch_bounds__(1024, 1)
void bv_init(double* stats, unsigned long long* minkey, int* comp,
             int* finalf, int* edgecnt, int* done)
{
    const int t = blockIdx.x * 1024 + threadIdx.x;   // grid 8 -> 8192 threads
    if (t < 2 * N) {
        minkey[t] = SENT;
        comp[t]   = t & (N - 1);
        finalf[t] = 0;
    }
    if (t < 6) stats[t] = 0.0;
    if (t < 2) { edgecnt[t] = 0; done[t] = 0; }
}

// One wave per row: find the row's min outgoing edge, atomicMin into its comp.
__global__ __launch_bounds__(1024, 1)
void bv_scan(const float* __restrict__ S, const int* __restrict__ intents,
             unsigned long long* __restrict__ minkey,
             const int* __restrict__ comp, const int* __restrict__ finalf,
             const int* __restrict__ done)
{
    const int g = blockIdx.y;
    if (done[g]) return;
    const int tid = threadIdx.x, lane = tid & 63, wid = tid >> 6;

    __shared__ int s_comp[N];
    __shared__ int s_int[N];
    const int* cg = comp + g * N;
    for (int i = tid; i < N; i += 1024) { s_comp[i] = cg[i]; s_int[i] = intents[i]; }
    __syncthreads();

    const int row = blockIdx.x * 16 + wid;
    const int ii  = s_int[row];
    // gold graph: edges never cross intent classes -> rows outside node-0's
    // class provably cannot affect node-0's component. Exact skip.
    if (g == 0 && ii != s_int[0]) return;
    const int ci = s_comp[row];
    if (finalf[g * N + ci]) return;               // component complete

    const float* Srow = S + (size_t)row * N;
    unsigned long long best = SENT;               // (mapf(w)<<32) | j
    #pragma unroll 4
    for (int k = 0; k < 16; ++k) {
        const float4 f4 = *reinterpret_cast<const float4*>(Srow + k * 256 + lane * 4);
        const float sv[4] = {f4.x, f4.y, f4.z, f4.w};
        #pragma unroll
        for (int m = 0; m < 4; ++m) {
            const int j = k * 256 + lane * 4 + m;
            if (s_comp[j] == ci) continue;        // internal (covers j==row)
            float w;
            if (!edge_w(g, sv[m], (s_int[j] == ii), w)) continue;
            const unsigned long long kk =
                ((unsigned long long)mapf(w) << 32) | (unsigned)j;
            if (kk < best) best = kk;
        }
    }
    #pragma unroll
    for (int d = 1; d < 64; d <<= 1) {
        const unsigned long long o = __shfl_xor(best, d, 64);
        if (o < best) best = o;
    }
    if (lane == 0 && best != SENT) {
        const unsigned wm = (unsigned)(best >> 32);
        const int j  = (int)(best & 0xFFFFFFFFu);
        const int lo = row < j ? row : j;
        const int hi = row < j ? j : row;
        // global strict total order: (w, lo, hi) -> unique MST
        const unsigned long long key =
            ((unsigned long long)wm << 24) | ((unsigned)lo << 12) | (unsigned)hi;
        atomicMin(&minkey[g * N + ci], key);
    }
}

// Star contraction: dedupe chosen edges, append to edge list, pointer-jump,
// relabel comps, reset minkey, detect completion.
__global__ __launch_bounds__(1024, 1)
void bv_merge(double* stats, unsigned long long* __restrict__ minkey,
              int* __restrict__ comp, int* __restrict__ finalf,
              unsigned long long* __restrict__ edgebuf, int* __restrict__ edgecnt,
              int* __restrict__ done)
{
    const int g = blockIdx.x;
    if (done[g]) return;
    const int tid = threadIdx.x;

    __shared__ int s_par[N];
    __shared__ int s_oth[N];
    __shared__ int s_merged;
    if (tid == 0) s_merged = 0;
    unsigned long long* mk = minkey + g * N;
    int* cg = comp + g * N;
    __syncthreads();

    // phase 1: parent pointers from chosen edges
    for (int c = tid; c < N; c += 1024) {
        const unsigned long long k = mk[c];
        if (k == SENT) {
            s_par[c] = c; s_oth[c] = c;
            finalf[g * N + c] = 1;                // no outgoing edge -> done forever
        } else {
            const int lo = (int)((k >> 12) & 0xFFFu);
            const int hi = (int)(k & 0xFFFu);
            const int clo = cg[lo], chi = cg[hi];
            const int d = (clo == c) ? chi : clo;
            s_par[c] = d; s_oth[c] = d;
        }
    }
    __syncthreads();
    // phase 2: break mutual pairs (exactly one 2-cycle per piece, at its min edge)
    for (int c = tid; c < N; c += 1024) {
        const int d = s_par[c];
        if (d != c && s_par[d] == c && c < d) s_par[c] = c;   // smaller idx = root
    }
    __syncthreads();
    // phase 3: dedupe + append edges (stats deferred to bv_count)
    for (int c = tid; c < N; c += 1024) {
        const unsigned long long k = mk[c];
        if (k == SENT) continue;
        s_merged = 1;                              // benign race, all write 1
        const int d = s_oth[c];
        const bool dup = (mk[d] == k) && (d < c);  // mutual: smaller comp keeps it
        if (!dup) {
            const int idx = atomicAdd(&edgecnt[g], 1);
            if (idx < EDGE_CAP) edgebuf[g * EDGE_CAP + idx] = k;
        }
    }
    __syncthreads();
    // phase 4: pointer jumping (concurrent reads of ancestors are benign)
    for (int r = 0; r < 12; ++r) {
        for (int c = tid; c < N; c += 1024) s_par[c] = s_par[s_par[c]];
        __syncthreads();
    }
    // phase 5: relabel nodes + reset minkey for next round
    for (int i = tid; i < N; i += 1024) {
        cg[i] = s_par[cg[i]];
        mk[i] = SENT;
    }
    if (tid == 0 && !s_merged) done[g] = 1;
}

// Count only edges in node-0's FINAL component (exact reference semantics).
__global__ __launch_bounds__(1024, 1)
void bv_count(const int* __restrict__ intents,
              const unsigned long long* __restrict__ edgebuf,
              const int* __restrict__ edgecnt, const int* __restrict__ comp,
              double* __restrict__ stats)
{
    const int g = blockIdx.x;
    const int tid = threadIdx.x, lane = tid & 63, wid = tid >> 6;
    __shared__ double s_acc[16][3];
    int n = edgecnt[g]; if (n > EDGE_CAP) n = EDGE_CAP;
    const int r0 = comp[g * N + 0];

    double A = 0.0, B = 0.0, W = 0.0;
    for (int e = tid; e < n; e += 1024) {
        const unsigned long long k = edgebuf[g * EDGE_CAP + e];
        const int lo = (int)((k >> 12) & 0xFFFu);
        const int hi = (int)(k & 0xFFFu);
        if (comp[g * N + lo] != r0) continue;      // outside node-0's component
        const float w = unmapf((unsigned)(k >> 24));
        if (g == 0) A += 1.0;
        else { if (intents[lo] == intents[hi]) A += 1.0; else B += 1.0; }
        W += (double)w;
    }
    #pragma unroll
    for (int d = 1; d < 64; d <<= 1) {
        A += __shfl_xor(A, d, 64); B += __shfl_xor(B, d, 64); W += __shfl_xor(W, d, 64);
    }
    if (lane == 0) { s_acc[wid][0] = A; s_acc[wid][1] = B; s_acc[wid][2] = W; }
    __syncthreads();
    if (tid == 0) {
        double a = 0, b = 0, w = 0;
        for (int q = 0; q < 16; ++q) { a += s_acc[q][0]; b += s_acc[q][1]; w += s_acc[q][2]; }
        stats[g * 3 + 0] = a;     // gold: a (count)      | viol: b (eq count)
        stats[g * 3 + 1] = b;     // gold: unused         | viol: c (neq count)
        stats[g * 3 + 2] = w;     // sum of edge weights
    }
}

__global__ void finalize_kernel(const double* __restrict__ ws,
                                float* __restrict__ out)
{
    const double a           = ws[0];
    const double sum_dj_gold = ws[2];
    const double b           = ws[3];
    const double c           = ws[4];
    const double sum_dj_viol = ws[5];

    const double gold_score = -sum_dj_gold;              // S = -w
    const double viol_score = -sum_dj_viol + b - 0.5 * c; // S = -w + eq - 0.5*neq
    const double delta = a - b + 0.5 * c;                // C=1, R=0.5
    const double obj   = delta + viol_score - gold_score;
    const double loss  = (delta > 0.0) ? fmax(0.0, obj) : 0.0;
    out[0] = (float)loss;
}

extern "C" void kernel_launch(void* const* d_in, const int* in_sizes, int n_in,
                              void* d_out, int out_size, void* d_ws, size_t ws_size,
                              hipStream_t stream)
{
    const float* S       = (const float*)d_in[0];
    const int*   intents = (const int*)d_in[1];
    float*       out     = (float*)d_out;

    char* w = (char*)d_ws;
    double*             stats   = (double*)w;                          // 48 B (pad 64)
    unsigned long long* minkey  = (unsigned long long*)(w + 64);       // 2*N*8 = 64 KiB
    unsigned long long* edgebuf = (unsigned long long*)(w + 64 + 2 * N * 8);          // 2*EDGE_CAP*8
    int*                comp    = (int*)(w + 64 + 2 * N * 8 + 2 * EDGE_CAP * 8);      // 2*N*4
    int*                finalf  = comp + 2 * N;                                        // 2*N*4
    int*                edgecnt = finalf + 2 * N;                                      // 2
    int*                done    = edgecnt + 2;                                         // 2

    hipLaunchKernelGGL(bv_init, dim3(8), dim3(1024), 0, stream,
                       stats, minkey, comp, finalf, edgecnt, done);
    for (int r = 0; r < ROUNDS; ++r) {
        hipLaunchKernelGGL(bv_scan, dim3(256, 2), dim3(1024), 0, stream,
                           S, intents, minkey, comp, finalf, done);
        hipLaunchKernelGGL(bv_merge, dim3(2), dim3(1024), 0, stream,
                           stats, minkey, comp, finalf, edgebuf, edgecnt, done);
    }
    hipLaunchKernelGGL(bv_count, dim3(2), dim3(1024), 0, stream,
                       intents, edgebuf, edgecnt, comp, stats);
    hipLaunchKernelGGL(finalize_kernel, dim3(1), dim3(1), 0, stream, stats, out);
}